// Round 7
// baseline (877.725 us; speedup 1.0000x reference)
//
#include <hip/hip_runtime.h>

#define NB 4
#define NH 16
#define SEQ 2048
#define DH 128
#define QT 128
#define KT 64
#define NTHREADS 512

typedef __attribute__((ext_vector_type(8))) _Float16 f16x8;
typedef __attribute__((ext_vector_type(4))) _Float16 f16x4;
typedef __attribute__((ext_vector_type(2))) _Float16 f16x2;
typedef __attribute__((ext_vector_type(4))) float f32x4;

static __device__ __forceinline__ f16x2 pkrtz(float x, float y) {
    return __builtin_bit_cast(f16x2, __builtin_amdgcn_cvt_pkrtz(x, y));
}
static __device__ __forceinline__ unsigned ubits(f16x2 v) {
    return __builtin_bit_cast(unsigned, v);
}

// scale 1/0.32 and log2(e) folded into Q at load time -> QK output is already in exp2 domain
static constexpr float CLOG2E = 3.125f * 1.44269504088896340736f;

// V^T LDS swizzle: row d (128 rows x 64 keys, no pad, row = 128B = 32 dwords).
// 8-half block kb8 stored at kb8 ^ dmix(d); verified conflict-free for staging
// writes (8B per lane) and PV b64 reads.
static __device__ __forceinline__ int vt_off(int d, int kb8, int sub4) {
    int dmix = (d & 7) ^ ((d >> 3) & 7);
    return (d << 6) + ((kb8 ^ dmix) << 3) + (sub4 << 2);
}

// K-tile: row-major [64][128] halfs (256B rows, no pad -> 16 KB). XOR swizzle:
// half-index col ^= (row&7)<<3 (16B granules). b128 reads: rows 0..7 hit 8
// distinct 16B slots (all 32 banks); rows 8..15 alias 2-way (free, m136).
// Numerically verified in R1. 8B alignment of writes preserved (XOR flips
// bits 3..5 of the half index only).
static __device__ __forceinline__ int k_off(int row, int colh) {
    return (row << 7) + (colh ^ ((row & 7) << 3));
}

__global__ __launch_bounds__(NTHREADS, 4)
void fattn_kernel(const float* __restrict__ Q, const float* __restrict__ K,
                  const float* __restrict__ V, float* __restrict__ O) {
    // double-buffered tiles: 2 x (16 KB K + 16 KB V^T) = 65536 B (ran in R1)
    __shared__ _Float16 lk[2][KT * DH];
    __shared__ _Float16 lvt[2][DH * KT];

    const int tid  = threadIdx.x;
    const int wave = tid >> 6;
    const int lane = tid & 63;
    const int l15  = lane & 15;
    const int quad = lane >> 4;

    // XCD swizzle: all 16 Q-tiles of one (b,h) on one XCD (K/V L2 locality).
    const int blk = blockIdx.x;              // 0..1023
    const int j   = blk >> 3;                // 0..127
    const int bh  = (blk & 7) + 8 * (j >> 4);
    const int qt  = j & 15;

    const size_t base = (size_t)bh * SEQ * DH;
    const float* Qb = Q + base;
    const float* Kb = K + base;
    const float* Vb = V + base;
    float*       Ob = O + base;

    // ---- Q fragments, B-operand layout: lane holds Q[q = l15][d = ks*32 + quad*8 + j] ----
    // Pre-scaled by CLOG2E so S^T comes out in the exp2 domain.
    f16x8 qf[4];
    {
        const int qrow = qt * QT + wave * 16 + l15;
        const float* qp = Qb + (size_t)qrow * DH + quad * 8;
#pragma unroll
        for (int ks = 0; ks < 4; ++ks) {
            float4 a = *(const float4*)(qp + ks * 32);
            float4 b = *(const float4*)(qp + ks * 32 + 4);
            f16x2 p0 = pkrtz(a.x * CLOG2E, a.y * CLOG2E);
            f16x2 p1 = pkrtz(a.z * CLOG2E, a.w * CLOG2E);
            f16x2 p2 = pkrtz(b.x * CLOG2E, b.y * CLOG2E);
            f16x2 p3 = pkrtz(b.z * CLOG2E, b.w * CLOG2E);
            qf[ks] = (f16x8){p0.x, p0.y, p1.x, p1.y, p2.x, p2.y, p3.x, p3.y};
        }
    }

    // O accumulator: PV output C-layout: lane holds O[q = quad*4+r][d = db*16 + l15]
    f32x4 oacc[8];
#pragma unroll
    for (int db = 0; db < 8; ++db) oacc[db] = (f32x4){0.f, 0.f, 0.f, 0.f};
    float m_i = -3.0e38f;   // per-lane: softmax state of q-row = l15 (replicated over quads)
    float l_i = 0.f;

    // staging decomposition: 512 threads, K/V tile = 64 rows x 128 cols fp32
    const int c4  = tid & 31;   // float4 column
    const int r16 = tid >> 5;   // rows r16*4 .. r16*4+3

    // ---- preload tile 0 into registers ----
    float4 kpf[4], vpf[4];
    {
        const float* kp = Kb + (size_t)(r16 * 4) * DH + c4 * 4;
        const float* vp = Vb + (size_t)(r16 * 4) * DH + c4 * 4;
#pragma unroll
        for (int p = 0; p < 4; ++p) {
            kpf[p] = *(const float4*)(kp + (size_t)p * DH);
            vpf[p] = *(const float4*)(vp + (size_t)p * DH);
        }
    }

    for (int kt0 = 0; kt0 < SEQ; kt0 += KT) {
        const int cb = (kt0 / KT) & 1;

        // ---- staged regs -> LDS buf[cb] (fused cvt fp32->fp16; V transposed +
        //      swizzled) — identical code to R0. Safe without a leading barrier:
        //      barrier(t-1) guarantees compute(t-2), the last readers of buf[cb],
        //      finished; concurrent compute(t-1) touches only buf[cb^1]. ----
        unsigned vh[4][2];
#pragma unroll
        for (int p = 0; p < 4; ++p) {
            const int r = r16 * 4 + p;
            uint2 kw;
            kw.x = ubits(pkrtz(kpf[p].x, kpf[p].y));
            kw.y = ubits(pkrtz(kpf[p].z, kpf[p].w));
            *(uint2*)&lk[cb][k_off(r, c4 * 4)] = kw;
            vh[p][0] = ubits(pkrtz(vpf[p].x, vpf[p].y));
            vh[p][1] = ubits(pkrtz(vpf[p].z, vpf[p].w));
        }
#pragma unroll
        for (int i = 0; i < 4; ++i) {        // column d = c4*4 + i, keys r16*4..+3
            const int jw = i >> 1, sh = (i & 1) * 16;
            unsigned e0 = (vh[0][jw] >> sh) & 0xFFFFu;
            unsigned e1 = (vh[1][jw] >> sh) & 0xFFFFu;
            unsigned e2 = (vh[2][jw] >> sh) & 0xFFFFu;
            unsigned e3 = (vh[3][jw] >> sh) & 0xFFFFu;
            uint2 w;
            w.x = e0 | (e1 << 16);
            w.y = e2 | (e3 << 16);
            const int d = c4 * 4 + i;
            *(uint2*)&lvt[cb][vt_off(d, r16 >> 1, r16 & 1)] = w;
        }
        __syncthreads();   // the ONLY barrier per tile: buf[cb] ready

        // ---- issue next tile's K loads (latency hides under QK + softmax) ----
        const bool more = (kt0 + KT) < SEQ;
        if (more) {
            const float* kp = Kb + (size_t)(kt0 + KT + r16 * 4) * DH + c4 * 4;
#pragma unroll
            for (int p = 0; p < 4; ++p) kpf[p] = *(const float4*)(kp + (size_t)p * DH);
        }

        // ---- S^T = K . Q^T : A = K-frag (m=key), B = Q-frag (n=q) ----
        // output lane: S[q = l15][key = g*16 + quad*4 + r]  == A-frag layout for PV!
        f32x4 sacc[4];
#pragma unroll
        for (int g = 0; g < 4; ++g) sacc[g] = (f32x4){0.f, 0.f, 0.f, 0.f};
#pragma unroll
        for (int g = 0; g < 4; ++g) {
#pragma unroll
            for (int ks = 0; ks < 4; ++ks) {
                f16x8 kf = *(const f16x8*)&lk[cb][k_off(g * 16 + l15, ks * 32 + quad * 8)];
                sacc[g] = __builtin_amdgcn_mfma_f32_16x16x32_f16(kf, qf[ks], sacc[g], 0, 0, 0);
            }
        }

        // ---- online softmax: each lane owns full row q=l15 locally (16 vals) + 2 shuffles ----
        float mx = sacc[0][0];
#pragma unroll
        for (int g = 0; g < 4; ++g)
#pragma unroll
            for (int r = 0; r < 4; ++r) mx = fmaxf(mx, sacc[g][r]);
        mx = fmaxf(mx, __shfl_xor(mx, 16));
        mx = fmaxf(mx, __shfl_xor(mx, 32));
        const float mnew = fmaxf(m_i, mx);
        const float alpha = __builtin_amdgcn_exp2f(m_i - mnew);
        m_i = mnew;

        float ps[4][4];
        float rs = 0.f;
#pragma unroll
        for (int g = 0; g < 4; ++g)
#pragma unroll
            for (int r = 0; r < 4; ++r) {
                ps[g][r] = __builtin_amdgcn_exp2f(sacc[g][r] - m_i);
                rs += ps[g][r];
            }
        rs += __shfl_xor(rs, 16);
        rs += __shfl_xor(rs, 32);
        l_i = l_i * alpha + rs;

        // ---- issue next tile's V loads (latency hides under PV) ----
        if (more) {
            const float* vp = Vb + (size_t)(kt0 + KT + r16 * 4) * DH + c4 * 4;
#pragma unroll
            for (int p = 0; p < 4; ++p) vpf[p] = *(const float4*)(vp + (size_t)p * DH);
        }

        // ---- rescale O by alpha of its own rows (q = quad*4+r, fetched via shuffle) ----
        float af[4];
#pragma unroll
        for (int r = 0; r < 4; ++r) af[r] = __shfl(alpha, (lane & 48) | (quad * 4 + r));
#pragma unroll
        for (int db = 0; db < 8; ++db)
#pragma unroll
            for (int r = 0; r < 4; ++r) oacc[db][r] *= af[r];

        // ---- O += P.V via 16x16x16 mfma: A = P (in regs!), B = V^T from LDS ----
        f16x4 pf[4];
#pragma unroll
        for (int g = 0; g < 4; ++g)
            pf[g] = (f16x4){(_Float16)ps[g][0], (_Float16)ps[g][1],
                            (_Float16)ps[g][2], (_Float16)ps[g][3]};
#pragma unroll
        for (int db = 0; db < 8; ++db) {
            const int d = db * 16 + l15;
#pragma unroll
            for (int g = 0; g < 4; ++g) {
                const int kb8 = g * 2 + (quad >> 1);
                f16x4 vb = *(const f16x4*)&lvt[cb][vt_off(d, kb8, quad & 1)];
                oacc[db] = __builtin_amdgcn_mfma_f32_16x16x16f16(pf[g], vb, oacc[db], 0, 0, 0);
            }
        }
    }

    // ---- epilogue: O = acc / l  (l_i lives at q=l15 lanes; shuffle to C-layout rows) ----
    const float inv = 1.0f / l_i;
    float invr[4];
#pragma unroll
    for (int r = 0; r < 4; ++r) invr[r] = __shfl(inv, (lane & 48) | (quad * 4 + r));
#pragma unroll
    for (int db = 0; db < 8; ++db)
#pragma unroll
        for (int r = 0; r < 4; ++r) {
            const int row = qt * QT + wave * 16 + quad * 4 + r;
            const int col = db * 16 + l15;
            Ob[(size_t)row * DH + col] = oacc[db][r] * invr[r];
        }
}

extern "C" void kernel_launch(void* const* d_in, const int* in_sizes, int n_in,
                              void* d_out, int out_size, void* d_ws, size_t ws_size,
                              hipStream_t stream) {
    const float* Q = (const float*)d_in[0];
    const float* K = (const float*)d_in[1];
    const float* V = (const float*)d_in[2];
    float* O = (float*)d_out;
    // masks (d_in[3..5]) and dropout_p (d_in[6]) unused per reference.
    const int nblocks = NB * NH * (SEQ / QT);   // 64 * 16 = 1024
    fattn_kernel<<<dim3(nblocks), dim3(NTHREADS), 0, stream>>>(Q, K, V, O);
}

// Round 8
// 429.056 us; speedup vs baseline: 2.0457x; 2.0457x over previous
//
#include <hip/hip_runtime.h>

#define NB 4
#define NH 16
#define SEQ 2048
#define DH 128
#define QT 256
#define KT 64
#define NTHREADS 1024
#define LKS 136   /* K-tile row stride in halfs: 272 B rows, 16B-aligned, conflict-free b128 reads */

typedef __attribute__((ext_vector_type(8))) _Float16 f16x8;
typedef __attribute__((ext_vector_type(4))) _Float16 f16x4;
typedef __attribute__((ext_vector_type(2))) _Float16 f16x2;
typedef __attribute__((ext_vector_type(4))) float f32x4;

static __device__ __forceinline__ f16x2 pkrtz(float x, float y) {
    return __builtin_bit_cast(f16x2, __builtin_amdgcn_cvt_pkrtz(x, y));
}
static __device__ __forceinline__ unsigned ubits(f16x2 v) {
    return __builtin_bit_cast(unsigned, v);
}

// scale 1/0.32 and log2(e) folded into Q at load time -> QK output is already in exp2 domain
static constexpr float CLOG2E = 3.125f * 1.44269504088896340736f;

// V^T LDS swizzle: row d (128 rows x 64 keys, no pad, row = 128B = 32 dwords).
// 8-half block kb8 stored at kb8 ^ dmix(d); conflict-free for PV b64 reads
// (verified R0); staging writes now dword-granular, 2-way aliased = free (m136).
static __device__ __forceinline__ int vt_off(int d, int kb8, int sub4) {
    int dmix = (d & 7) ^ ((d >> 3) & 7);
    return (d << 6) + ((kb8 ^ dmix) << 3) + (sub4 << 2);
}

__global__ __launch_bounds__(NTHREADS, 4)
void fattn_kernel(const float* __restrict__ Q, const float* __restrict__ K,
                  const float* __restrict__ V, float* __restrict__ O) {
    __shared__ _Float16 lk[KT][LKS];     // K tile, row-major [key][d], fp16
    __shared__ _Float16 lvt[DH * KT];    // V^T tile, swizzled, fp16

    const int tid  = threadIdx.x;
    const int wave = tid >> 6;           // 0..15
    const int lane = tid & 63;
    const int l15  = lane & 15;
    const int quad = lane >> 4;

    // XCD mapping: all 8 Q-tile blocks of one (b,h) on one XCD (K/V L2 locality).
    const int blk = blockIdx.x;              // 0..511
    const int bh  = (blk & 7) + 8 * (blk >> 6);
    const int qt  = (blk >> 3) & 7;

    const size_t base = (size_t)bh * SEQ * DH;
    const float* Qb = Q + base;
    const float* Kb = K + base;
    const float* Vb = V + base;
    float*       Ob = O + base;

    // ---- Q fragments, B-operand layout: lane holds Q[q = l15][d = ks*32 + quad*8 + j] ----
    // Pre-scaled by CLOG2E so S^T comes out in the exp2 domain. Per-wave code
    // identical to the verified R0 kernel; wave now indexes 16 of 256 rows.
    f16x8 qf[4];
    {
        const int qrow = qt * QT + wave * 16 + l15;
        const float* qp = Qb + (size_t)qrow * DH + quad * 8;
#pragma unroll
        for (int ks = 0; ks < 4; ++ks) {
            float4 a = *(const float4*)(qp + ks * 32);
            float4 b = *(const float4*)(qp + ks * 32 + 4);
            f16x2 p0 = pkrtz(a.x * CLOG2E, a.y * CLOG2E);
            f16x2 p1 = pkrtz(a.z * CLOG2E, a.w * CLOG2E);
            f16x2 p2 = pkrtz(b.x * CLOG2E, b.y * CLOG2E);
            f16x2 p3 = pkrtz(b.z * CLOG2E, b.w * CLOG2E);
            qf[ks] = (f16x8){p0.x, p0.y, p1.x, p1.y, p2.x, p2.y, p3.x, p3.y};
        }
    }

    // O accumulator: PV output C-layout: lane holds O[q = quad*4+r][d = db*16 + l15]
    f32x4 oacc[8];
#pragma unroll
    for (int db = 0; db < 8; ++db) oacc[db] = (f32x4){0.f, 0.f, 0.f, 0.f};
    float m_i = -3.0e38f;   // per-lane: softmax state of q-row = l15 (replicated over quads)
    float l_i = 0.f;

    // staging decomposition: 1024 threads, K/V tile = 64 rows x 128 cols fp32.
    // Per-thread share HALVES vs R0: 2 rows (kpf[2]/vpf[2]) instead of 4.
    const int c4  = tid & 31;   // float4 column
    const int r32 = tid >> 5;   // rows r32*2 .. r32*2+1

    // ---- preload tile 0 into registers ----
    float4 kpf[2], vpf[2];
    {
        const float* kp = Kb + (size_t)(r32 * 2) * DH + c4 * 4;
        const float* vp = Vb + (size_t)(r32 * 2) * DH + c4 * 4;
#pragma unroll
        for (int p = 0; p < 2; ++p) {
            kpf[p] = *(const float4*)(kp + (size_t)p * DH);
            vpf[p] = *(const float4*)(vp + (size_t)p * DH);
        }
    }

    for (int kt0 = 0; kt0 < SEQ; kt0 += KT) {
        __syncthreads();   // b1: previous tile's readers done

        // ---- write staged regs -> LDS (cvt fp32->fp16; V transposed + swizzled) ----
        unsigned vh[2][2];
#pragma unroll
        for (int p = 0; p < 2; ++p) {
            const int r = r32 * 2 + p;
            uint2 kw;
            kw.x = ubits(pkrtz(kpf[p].x, kpf[p].y));
            kw.y = ubits(pkrtz(kpf[p].z, kpf[p].w));
            *(uint2*)&lk[r][c4 * 4] = kw;
            vh[p][0] = ubits(pkrtz(vpf[p].x, vpf[p].y));
            vh[p][1] = ubits(pkrtz(vpf[p].z, vpf[p].w));
        }
#pragma unroll
        for (int i = 0; i < 4; ++i) {        // column d = c4*4 + i, keys r32*2..+1
            const int jw = i >> 1, sh = (i & 1) * 16;
            unsigned e0 = (vh[0][jw] >> sh) & 0xFFFFu;
            unsigned e1 = (vh[1][jw] >> sh) & 0xFFFFu;
            const int d   = c4 * 4 + i;
            // keys r32*2..+1 live in 8-key block kb8 = r32>>2, 4-key half
            // sub4 = (r32>>1)&1, intra-half offset (r32&1)*2 halfs (dword-aligned).
            const int idx = vt_off(d, r32 >> 2, (r32 >> 1) & 1) + (r32 & 1) * 2;
            *(unsigned*)&lvt[idx] = e0 | (e1 << 16);
        }
        __syncthreads();   // b2: lk/lvt ready

        // ---- issue next tile's K loads (latency hides under QK + softmax) ----
        const bool more = (kt0 + KT) < SEQ;
        if (more) {
            const float* kp = Kb + (size_t)(kt0 + KT + r32 * 2) * DH + c4 * 4;
#pragma unroll
            for (int p = 0; p < 2; ++p) kpf[p] = *(const float4*)(kp + (size_t)p * DH);
        }

        // ---- S^T = K . Q^T : A = K-frag (m=key), B = Q-frag (n=q) ----
        // output lane: S[q = l15][key = g*16 + quad*4 + r]  == A-frag layout for PV!
        f32x4 sacc[4];
#pragma unroll
        for (int g = 0; g < 4; ++g) sacc[g] = (f32x4){0.f, 0.f, 0.f, 0.f};
#pragma unroll
        for (int g = 0; g < 4; ++g) {
#pragma unroll
            for (int ks = 0; ks < 4; ++ks) {
                f16x8 kf = *(const f16x8*)&lk[g * 16 + l15][ks * 32 + quad * 8];
                sacc[g] = __builtin_amdgcn_mfma_f32_16x16x32_f16(kf, qf[ks], sacc[g], 0, 0, 0);
            }
        }

        // ---- online softmax: each lane owns full row q=l15 locally (16 vals) + 2 shuffles ----
        float mx = sacc[0][0];
#pragma unroll
        for (int g = 0; g < 4; ++g)
#pragma unroll
            for (int r = 0; r < 4; ++r) mx = fmaxf(mx, sacc[g][r]);
        mx = fmaxf(mx, __shfl_xor(mx, 16));
        mx = fmaxf(mx, __shfl_xor(mx, 32));
        const float mnew = fmaxf(m_i, mx);
        const float alpha = __builtin_amdgcn_exp2f(m_i - mnew);
        m_i = mnew;

        float ps[4][4];
        float rs = 0.f;
#pragma unroll
        for (int g = 0; g < 4; ++g)
#pragma unroll
            for (int r = 0; r < 4; ++r) {
                ps[g][r] = __builtin_amdgcn_exp2f(sacc[g][r] - m_i);
                rs += ps[g][r];
            }
        rs += __shfl_xor(rs, 16);
        rs += __shfl_xor(rs, 32);
        l_i = l_i * alpha + rs;

        // ---- issue next tile's V loads (latency hides under PV) ----
        if (more) {
            const float* vp = Vb + (size_t)(kt0 + KT + r32 * 2) * DH + c4 * 4;
#pragma unroll
            for (int p = 0; p < 2; ++p) vpf[p] = *(const float4*)(vp + (size_t)p * DH);
        }

        // ---- rescale O by alpha of its own rows (q = quad*4+r, fetched via shuffle) ----
        float af[4];
#pragma unroll
        for (int r = 0; r < 4; ++r) af[r] = __shfl(alpha, (lane & 48) | (quad * 4 + r));
#pragma unroll
        for (int db = 0; db < 8; ++db)
#pragma unroll
            for (int r = 0; r < 4; ++r) oacc[db][r] *= af[r];

        // ---- O += P.V via 16x16x16 mfma: A = P (in regs!), B = V^T from LDS ----
        f16x4 pf[4];
#pragma unroll
        for (int g = 0; g < 4; ++g)
            pf[g] = (f16x4){(_Float16)ps[g][0], (_Float16)ps[g][1],
                            (_Float16)ps[g][2], (_Float16)ps[g][3]};
#pragma unroll
        for (int db = 0; db < 8; ++db) {
            const int d = db * 16 + l15;
#pragma unroll
            for (int g = 0; g < 4; ++g) {
                const int kb8 = g * 2 + (quad >> 1);
                f16x4 vb = *(const f16x4*)&lvt[vt_off(d, kb8, quad & 1)];
                oacc[db] = __builtin_amdgcn_mfma_f32_16x16x16f16(pf[g], vb, oacc[db], 0, 0, 0);
            }
        }
    }

    // ---- epilogue: O = acc / l  (l_i lives at q=l15 lanes; shuffle to C-layout rows) ----
    const float inv = 1.0f / l_i;
    float invr[4];
#pragma unroll
    for (int r = 0; r < 4; ++r) invr[r] = __shfl(inv, (lane & 48) | (quad * 4 + r));
#pragma unroll
    for (int db = 0; db < 8; ++db)
#pragma unroll
        for (int r = 0; r < 4; ++r) {
            const int row = qt * QT + wave * 16 + quad * 4 + r;
            const int col = db * 16 + l15;
            Ob[(size_t)row * DH + col] = oacc[db][r] * invr[r];
        }
}

extern "C" void kernel_launch(void* const* d_in, const int* in_sizes, int n_in,
                              void* d_out, int out_size, void* d_ws, size_t ws_size,
                              hipStream_t stream) {
    const float* Q = (const float*)d_in[0];
    const float* K = (const float*)d_in[1];
    const float* V = (const float*)d_in[2];
    float* O = (float*)d_out;
    // masks (d_in[3..5]) and dropout_p (d_in[6]) unused per reference.
    const int nblocks = NB * NH * (SEQ / QT);   // 64 * 8 = 512
    fattn_kernel<<<dim3(nblocks), dim3(NTHREADS), 0, stream>>>(Q, K, V, O);
}